// Round 6
// baseline (235.168 us; speedup 1.0000x reference)
//
#include <hip/hip_runtime.h>
#include <stdint.h>

#define BDIM_C 256   // convert kernel block
#define BDIM_A 512   // attention block: 8 waves x 16 q-rows

typedef __attribute__((ext_vector_type(8))) short short8;   // 8 bf16
typedef __attribute__((ext_vector_type(4))) float f32x4;    // MFMA C/D

// fp32 -> bf16 round-to-nearest-even (finite inputs)
__device__ __forceinline__ unsigned f2bf(float f) {
    union { float f; unsigned u; } a; a.f = f;
    unsigned r = a.u + 0x7fffu + ((a.u >> 16) & 1u);
    return (r >> 16) & 0xffffu;
}
__device__ __forceinline__ float f4e(float4 v, int e) {
    return e == 0 ? v.x : e == 1 ? v.y : e == 2 ? v.z : v.w;
}
__device__ __forceinline__ unsigned u4e(uint4 v, int e) {
    return e == 0 ? v.x : e == 1 ? v.y : e == 2 ? v.z : v.w;
}
__device__ __forceinline__ uint2 shfl_u2(uint2 v, int src) {
    uint2 r;
    r.x = (unsigned)__shfl((int)v.x, src);
    r.y = (unsigned)__shfl((int)v.y, src);
    return r;
}
// bf16-vs-fp32 vote on first 64 words (low halves bf16-plausible vs noise)
__device__ __forceinline__ bool detect_bf16(const void* p) {
    unsigned w = ((const unsigned*)p)[threadIdx.x & 63];
    unsigned lo = w & 0xffffu, ex = (lo >> 7) & 0xffu;
    bool pl = (lo == 0u) || (ex >= 0x68u && ex <= 0x86u);
    return __popcll(__ballot(pl)) >= 40;
}

// ---- kernel 1: K and V -> bf16 workspace in ONE launch ----
__global__ __launch_bounds__(BDIM_C)
void convert2_kernel(const void* __restrict__ srcK, const void* __restrict__ srcV,
                     uint2* __restrict__ dstK, uint2* __restrict__ dstV, int n4)
{
    bool isBf = detect_bf16(srcK);
    int stride = gridDim.x * BDIM_C;
    for (int t = blockIdx.x * BDIM_C + threadIdx.x; t < 2 * n4; t += stride) {
        const void* s = (t < n4) ? srcK : srcV;
        uint2* d = (t < n4) ? dstK : dstV;
        int idx = (t < n4) ? t : t - n4;
        uint2 o;
        if (isBf) {
            o = ((const uint2*)s)[idx];
        } else {
            float4 v = ((const float4*)s)[idx];
            o.x = f2bf(v.x) | (f2bf(v.y) << 16);
            o.y = f2bf(v.z) | (f2bf(v.w) << 16);
        }
        d[idx] = o;
    }
}

// ---- kernel 2: block-sparse attention ----
// One WG per (bh,i): 512 threads = 8 waves, each wave owns 16 q-rows
// (halved per-wave registers -> 4 waves/SIMD occupancy). Per active j:
//   barrier -> stage K(bf16)->ldsK + V^T(bf16)->ldsV -> barrier
//   -> GEMM1 S^T = K.Q^T -> per-q softmax (2 shuffles) -> pack P bf16
//   -> P C-layout -> A-layout via cross-quad shuffles -> GEMM2 O += P.V
template<bool QF32, bool KVF32>
__device__ __forceinline__ void attn_body(const void* Qv, const void* Kv,
                                          const void* Vv,
                                          const unsigned char* Mb, bool maskByte,
                                          void* Ov, char* ldsK, char* ldsV,
                                          int bh, int i)
{
    constexpr int S = 2048, D = 128;
    const int tid  = threadIdx.x;
    const int lane = tid & 63;
    const int wave = tid >> 6;        // 0..7
    const int quad = lane >> 4;
    const int l16  = lane & 15;

    const int qb0 = wave * 16;        // 16 q-rows per wave
    const size_t qrowbase = ((size_t)bh * S + (size_t)i * 128) * D;

    // ---- Q fragments (B-operand of GEMM1), reused across j ----
    short8 qf[4];
    {
        int qrow = qb0 + l16;
#pragma unroll
        for (int ks = 0; ks < 4; ++ks) {
            int dof = ks * 32 + quad * 8;
            if constexpr (QF32) {
                const float* qp = (const float*)Qv + qrowbase + (size_t)qrow * D + dof;
                float4 f0 = *(const float4*)qp;
                float4 f1 = *(const float4*)(qp + 4);
                short8 v;
                v[0] = (short)f2bf(f0.x); v[1] = (short)f2bf(f0.y);
                v[2] = (short)f2bf(f0.z); v[3] = (short)f2bf(f0.w);
                v[4] = (short)f2bf(f1.x); v[5] = (short)f2bf(f1.y);
                v[6] = (short)f2bf(f1.z); v[7] = (short)f2bf(f1.w);
                qf[ks] = v;
            } else {
                qf[ks] = *(const short8*)((const unsigned short*)Qv
                          + qrowbase + (size_t)qrow * D + dof);
            }
        }
    }

    f32x4 accO[8];
#pragma unroll
    for (int b = 0; b < 8; ++b)
        accO[b] = (f32x4){0.f, 0.f, 0.f, 0.f};

    const float C2 = 0.08838834764831845f * 1.44269504088896f; // rsqrt(128)*log2e
    const int srcA = l16 + ((quad & 1) << 5);
    const int srcB = srcA + 16;
    const bool hiMs = (quad >> 1) != 0;

    for (int j = 0; j < 16; ++j) {
        bool active = maskByte ? (Mb[i * 16 + j] != 0)
                               : (((const int*)Mb)[i * 16 + j] != 0);
        if (!active) continue;   // WG-uniform

        __syncthreads();   // previous iteration's LDS reads complete
        const size_t kb = ((size_t)bh * S + (size_t)j * 128) * D;

        // ---- stage K tile (row-major 16B chunks, XOR swizzle by row) ----
        if constexpr (KVF32) {
#pragma unroll
            for (int it = 0; it < 8; ++it) {
                int f = it * BDIM_A + tid;   // float4 idx 0..4095 (32 per row)
                int r = f >> 5, c4 = f & 31;
                float4 v = ((const float4*)((const float*)Kv + kb))[f];
                uint2 pk;
                pk.x = f2bf(v.x) | (f2bf(v.y) << 16);
                pk.y = f2bf(v.z) | (f2bf(v.w) << 16);
                int ch = c4 >> 1;
                *(uint2*)(ldsK + r * 256 + ((ch ^ (r & 7)) << 4)
                          + ((c4 & 1) << 3)) = pk;
            }
        } else {
#pragma unroll
            for (int it = 0; it < 4; ++it) {
                int id = it * BDIM_A + tid;  // uint4 idx 0..2047 (16 per row)
                int r = id >> 4, ch = id & 15;
                uint4 v = ((const uint4*)((const unsigned short*)Kv + kb))[id];
                *(uint4*)(ldsK + r * 256 + ((ch ^ (r & 7)) << 4)) = v;
            }
        }

        // ---- stage V^T (512 slots: pp=s-group, dc=d-chunk; 8B writes) ----
        {
            int pp = tid & 31, dc = tid >> 5;
            if constexpr (KVF32) {
                const float* vb = (const float*)Vv + kb + (size_t)(4 * pp) * D + dc * 8;
                float4 ra[4], rb[4];
#pragma unroll
                for (int r = 0; r < 4; ++r) {
                    ra[r] = *(const float4*)(vb + (size_t)r * D);
                    rb[r] = *(const float4*)(vb + (size_t)r * D + 4);
                }
#pragma unroll
                for (int e = 0; e < 8; ++e) {
                    float v0 = (e < 4) ? f4e(ra[0], e) : f4e(rb[0], e - 4);
                    float v1 = (e < 4) ? f4e(ra[1], e) : f4e(rb[1], e - 4);
                    float v2 = (e < 4) ? f4e(ra[2], e) : f4e(rb[2], e - 4);
                    float v3 = (e < 4) ? f4e(ra[3], e) : f4e(rb[3], e - 4);
                    uint2 pk;
                    pk.x = f2bf(v0) | (f2bf(v1) << 16);
                    pk.y = f2bf(v2) | (f2bf(v3) << 16);
                    int d = dc * 8 + e;
                    *(uint2*)(ldsV + d * 256 + (((pp >> 1) ^ (d & 7)) << 4)
                              + ((pp & 1) << 3)) = pk;
                }
            } else {
                const unsigned short* vb = (const unsigned short*)Vv + kb
                                           + (size_t)(4 * pp) * D + dc * 8;
                uint4 r0 = *(const uint4*)(vb);
                uint4 r1 = *(const uint4*)(vb + D);
                uint4 r2 = *(const uint4*)(vb + 2 * D);
                uint4 r3 = *(const uint4*)(vb + 3 * D);
#pragma unroll
                for (int e = 0; e < 8; ++e) {
                    unsigned h0 = u4e(r0, e >> 1), h1 = u4e(r1, e >> 1);
                    unsigned h2 = u4e(r2, e >> 1), h3 = u4e(r3, e >> 1);
                    if (e & 1) { h0 >>= 16; h1 >>= 16; h2 >>= 16; h3 >>= 16; }
                    uint2 pk;
                    pk.x = (h0 & 0xffffu) | (h1 << 16);
                    pk.y = (h2 & 0xffffu) | (h3 << 16);
                    int d = dc * 8 + e;
                    *(uint2*)(ldsV + d * 256 + (((pp >> 1) ^ (d & 7)) << 4)
                              + ((pp & 1) << 3)) = pk;
                }
            }
        }
        __syncthreads();

        // ---- GEMM1: S^T = K . Q^T (16 q-rows per wave) ----
        f32x4 accS[8];
#pragma unroll
        for (int mt = 0; mt < 8; ++mt)
            accS[mt] = (f32x4){0.f, 0.f, 0.f, 0.f};

#pragma unroll
        for (int mt = 0; mt < 8; ++mt) {
            int r = mt * 16 + l16;       // kcol
            short8 kf[4];
#pragma unroll
            for (int ks = 0; ks < 4; ++ks) {
                int c = ks * 4 + quad;
                kf[ks] = *(const short8*)(ldsK + r * 256 + ((c ^ (r & 7)) << 4));
            }
#pragma unroll
            for (int ks = 0; ks < 4; ++ks)
                accS[mt] = __builtin_amdgcn_mfma_f32_16x16x32_bf16(
                    kf[ks], qf[ks], accS[mt], 0, 0, 0);
        }

        // ---- per-q softmax + pack P to bf16 ----
        uint2 p2[8];
        {
            float mx = -3.0e38f;
#pragma unroll
            for (int mt = 0; mt < 8; ++mt)
#pragma unroll
                for (int rr = 0; rr < 4; ++rr)
                    mx = fmaxf(mx, accS[mt][rr]);
            mx = fmaxf(mx, __shfl_xor(mx, 16));
            mx = fmaxf(mx, __shfl_xor(mx, 32));
            float mc = mx * C2;
            float sum = 0.f;
#pragma unroll
            for (int mt = 0; mt < 8; ++mt)
#pragma unroll
                for (int rr = 0; rr < 4; ++rr) {
                    float p = exp2f(accS[mt][rr] * C2 - mc);
                    accS[mt][rr] = p;
                    sum += p;
                }
            sum += __shfl_xor(sum, 16);
            sum += __shfl_xor(sum, 32);
            float rinv = 1.0f / sum;
#pragma unroll
            for (int mt = 0; mt < 8; ++mt) {
                p2[mt].x = f2bf(accS[mt][0] * rinv) | (f2bf(accS[mt][1] * rinv) << 16);
                p2[mt].y = f2bf(accS[mt][2] * rinv) | (f2bf(accS[mt][3] * rinv) << 16);
            }
        }

        // ---- GEMM2: O += P.V (P via cross-quad shuffles, V^T from LDS) ----
#pragma unroll
        for (int ks = 0; ks < 4; ++ks) {
            short8 pf;
            {
                uint2 a0 = shfl_u2(p2[2 * ks + 0], srcA);
                uint2 a1 = shfl_u2(p2[2 * ks + 1], srcA);
                uint2 b0 = shfl_u2(p2[2 * ks + 0], srcB);
                uint2 b1 = shfl_u2(p2[2 * ks + 1], srcB);
                uint2 lo, hi;
                lo.x = hiMs ? a1.x : a0.x;  lo.y = hiMs ? a1.y : a0.y;
                hi.x = hiMs ? b1.x : b0.x;  hi.y = hiMs ? b1.y : b0.y;
                union { uint4 u; short8 s; } w;
                w.u.x = lo.x; w.u.y = lo.y; w.u.z = hi.x; w.u.w = hi.y;
                pf = w.s;
            }
#pragma unroll
            for (int dt = 0; dt < 8; ++dt) {
                int d = dt * 16 + l16;
                int c = ks * 4 + quad;
                short8 vf = *(const short8*)(ldsV + d * 256 + ((c ^ (d & 7)) << 4));
                accO[dt] = __builtin_amdgcn_mfma_f32_16x16x32_bf16(
                    pf, vf, accO[dt], 0, 0, 0);
            }
        }
    } // j loop

    // ---- store O (C-layout: rows quad*4+rr, col l16) ----
#pragma unroll
    for (int rr = 0; rr < 4; ++rr) {
        int qrow = qb0 + quad * 4 + rr;
#pragma unroll
        for (int dt = 0; dt < 8; ++dt) {
            size_t idx = qrowbase + (size_t)qrow * D + dt * 16 + l16;
            if constexpr (QF32)
                ((float*)Ov)[idx] = accO[dt][rr];
            else
                ((unsigned short*)Ov)[idx] = (unsigned short)f2bf(accO[dt][rr]);
        }
    }
}

// XCD swizzle: all 16 i-blocks of a bh share blockIdx%8 -> same XCD L2
__device__ __forceinline__ void swizzle_bhi(int blk, int& bh, int& i) {
    bh = ((blk >> 7) << 3) | (blk & 7);
    i  = (blk >> 3) & 15;
}

__global__ __launch_bounds__(BDIM_A, 4)
void attn_ws(const void* __restrict__ Q, const unsigned short* __restrict__ Kb,
             const unsigned short* __restrict__ Vb,
             const unsigned char* __restrict__ Mb, void* __restrict__ O)
{
    __shared__ uint4 ldsK4[2048];  // 32 KiB
    __shared__ uint4 ldsV4[2048];  // 32 KiB
    int bh, i; swizzle_bhi(blockIdx.x, bh, i);
    bool qBf = detect_bf16(Q);
    unsigned mu = ((const unsigned*)Mb)[threadIdx.x & 63];
    bool maskByte = (__ballot((mu & 0xFFFFFF00u) != 0u) != 0ull);
    if (qBf)
        attn_body<false, false>(Q, Kb, Vb, Mb, maskByte, O,
                                (char*)ldsK4, (char*)ldsV4, bh, i);
    else
        attn_body<true, false>(Q, Kb, Vb, Mb, maskByte, O,
                               (char*)ldsK4, (char*)ldsV4, bh, i);
}

__global__ __launch_bounds__(BDIM_A, 4)
void attn_direct(const void* __restrict__ Q, const void* __restrict__ K,
                 const void* __restrict__ V,
                 const unsigned char* __restrict__ Mb, void* __restrict__ O)
{
    __shared__ uint4 ldsK4[2048];
    __shared__ uint4 ldsV4[2048];
    int bh, i; swizzle_bhi(blockIdx.x, bh, i);
    bool qBf = detect_bf16(Q);
    unsigned mu = ((const unsigned*)Mb)[threadIdx.x & 63];
    bool maskByte = (__ballot((mu & 0xFFFFFF00u) != 0u) != 0ull);
    if (qBf)
        attn_body<false, false>(Q, K, V, Mb, maskByte, O,
                                (char*)ldsK4, (char*)ldsV4, bh, i);
    else
        attn_body<true, true>(Q, K, V, Mb, maskByte, O,
                              (char*)ldsK4, (char*)ldsV4, bh, i);
}

extern "C" void kernel_launch(void* const* d_in, const int* in_sizes, int n_in,
                              void* d_out, int out_size, void* d_ws, size_t ws_size,
                              hipStream_t stream) {
    const int NK = 2 * 16 * 2048 * 128;           // elements per K / V tensor
    const size_t need = (size_t)NK * 2 * 2;       // two bf16 tensors
    if (ws_size >= need) {
        unsigned short* Kb = (unsigned short*)d_ws;
        unsigned short* Vb = Kb + NK;
        convert2_kernel<<<4096, BDIM_C, 0, stream>>>(d_in[1], d_in[2],
                                                     (uint2*)Kb, (uint2*)Vb, NK / 4);
        attn_ws<<<512, BDIM_A, 0, stream>>>(d_in[0], Kb, Vb,
                                            (const unsigned char*)d_in[3], d_out);
    } else {
        attn_direct<<<512, BDIM_A, 0, stream>>>(d_in[0], d_in[1], d_in[2],
                                                (const unsigned char*)d_in[3], d_out);
    }
}